// Round 3
// baseline (375.865 us; speedup 1.0000x reference)
//
#include <hip/hip_runtime.h>
#include <math.h>

#define LQ 40000
#define DMODEL 256
#define NHD 8
#define NPT 4
#define DHD 32
#define HSP 200
#define WSP 200
#define NSTRIP (LQ / 16)   // 2500
#define GEMM_GRID 512      // 2 blocks/CU, all resident

typedef short s16x8 __attribute__((ext_vector_type(8)));
typedef float f32x4 __attribute__((ext_vector_type(4)));

__device__ __forceinline__ unsigned short f2b(float f) {
    unsigned u = __builtin_bit_cast(unsigned, f);
    u += 0x7FFFu + ((u >> 16) & 1u);   // round-to-nearest-even
    return (unsigned short)(u >> 16);
}
__device__ __forceinline__ float b2f(unsigned short u) {
    return __builtin_bit_cast(float, ((unsigned)u) << 16);
}
__device__ __forceinline__ void pk8(const float4& v0, const float4& v1,
                                    unsigned short* o) {
    o[0] = f2b(v0.x); o[1] = f2b(v0.y); o[2] = f2b(v0.z); o[3] = f2b(v0.w);
    o[4] = f2b(v1.x); o[5] = f2b(v1.y); o[6] = f2b(v1.z); o[7] = f2b(v1.w);
}

// ---------------------------------------------------------------------------
// Fragment layouts (16x16x32 bf16 MFMA):
//   A-frag buffer: elem(row, k) at  (row/16)*4096 + ks*512 + lane*8 + j
//       where ks=k/32, quad=(k/8)&3, j=k&7, lane=quad*16+(row&15).
//   W-frag buffer: elem(col, k) at  slot*4096 + ks*512 + lane*8 + j
//       where slot=coltile, lane=quad*16+(col&15). Coalesced b128 per (c,ks).
// ---------------------------------------------------------------------------

// Pre-convert all weights to bf16 fragment order.
// slots: 0-15 W_value, 16-21 [W_off;W_attn] (split 64), 22-37 W_out.
__global__ __launch_bounds__(256) void convert_weights(
    const float* __restrict__ Wv, const float* __restrict__ Woff,
    const float* __restrict__ Wattn, const float* __restrict__ Wout,
    unsigned short* __restrict__ dst)
{
    int u = blockIdx.x * 256 + threadIdx.x;      // 38*8*64 = 19456 exactly
    int lane = u & 63, ks = (u >> 6) & 7, slot = u >> 9;
    int l15 = lane & 15, quad = lane >> 4;
    const float* src;
    if (slot < 16) {
        src = Wv + (size_t)(slot * 16 + l15) * 256;
    } else if (slot < 22) {
        int col = (slot - 16) * 16 + l15;
        src = (col < 64) ? Woff + (size_t)col * 256
                         : Wattn + (size_t)(col - 64) * 256;
    } else {
        src = Wout + (size_t)((slot - 22) * 16 + l15) * 256;
    }
    int k0 = ks * 32 + quad * 8;
    float4 v0 = *(const float4*)(src + k0);
    float4 v1 = *(const float4*)(src + k0 + 4);
    union { unsigned short u16[8]; uint4 v; } tmp;
    pk8(v0, v1, tmp.u16);
    *(uint4*)(dst + (size_t)u * 8) = tmp.v;
}

// ---------------------------------------------------------------------------
// Persistent software-pipelined row-strip GEMM, fp32 A fused in-register.
// 512 blocks x 4 waves; waves share the strip (L1 broadcast), wave owns
// TPW coltiles. First NBRES coltiles' B-fragments live in VGPRs; the rest
// are re-issued from L2 each iteration alongside the A prefetch (latency
// hides under MFMA). Per iteration: wait+convert current strip, ISSUE next
// strip's loads, then MFMA+store.
// CMODE 0: C fp32 row-major [M x NT*16].
// CMODE 1: C bf16 value layout [head][pixel][32ch].
// CMODE 2: C fp32 head-major raw layout [8][LQ][12]  (8 offs + 4 logits).
// ---------------------------------------------------------------------------
template <int NT, int TPW, int NBRES, int CMODE, bool HasA2>
__global__ __launch_bounds__(256, 2) void gemm_fused(
    const float* __restrict__ A, const float* __restrict__ A2,
    const unsigned short* __restrict__ Wf,
    const float* __restrict__ b1, const float* __restrict__ b2, int split,
    void* __restrict__ Cv)
{
    const int t = threadIdx.x;
    const int wave = t >> 6, lane = t & 63;
    const int l15 = lane & 15, quad = lane >> 4;

    // Resident B fragments + bias (loaded once per block)
    s16x8 bf[NBRES][8];
    float bias[TPW];
#pragma unroll
    for (int j = 0; j < TPW; ++j) {
        bias[j] = 0.f;
        int c = wave * TPW + j;
        if (c < NT) {
            int col = c * 16 + l15;
            bias[j] = (col < split) ? b1[col] : b2[col - split];
        }
    }
#pragma unroll
    for (int j = 0; j < NBRES; ++j) {
        int c = wave * TPW + j;
        if (c < NT) {
#pragma unroll
            for (int ks = 0; ks < 8; ++ks)
                bf[j][ks] = *(const s16x8*)&Wf[(size_t)(c * 8 + ks) * 512 + lane * 8];
        }
    }

    float4 p0[8], p1[8], q0[8], q1[8];
    s16x8 bs[TPW > NBRES ? (TPW - NBRES) : 1][8];

    auto issue = [&](int gs) {
        const float* base = A + ((size_t)gs * 16 + l15) * 256;
#pragma unroll
        for (int ks = 0; ks < 8; ++ks) {
            const int k0 = ks * 32 + quad * 8;
            p0[ks] = *(const float4*)(base + k0);
            p1[ks] = *(const float4*)(base + k0 + 4);
        }
        if constexpr (HasA2) {
            const float* base2 = A2 + ((size_t)gs * 16 + l15) * 256;
#pragma unroll
            for (int ks = 0; ks < 8; ++ks) {
                const int k0 = ks * 32 + quad * 8;
                q0[ks] = *(const float4*)(base2 + k0);
                q1[ks] = *(const float4*)(base2 + k0 + 4);
            }
        }
    };
    auto issueB = [&]() {
        if constexpr (TPW > NBRES) {
#pragma unroll
            for (int j = NBRES; j < TPW; ++j) {
                int c = wave * TPW + j;
                if (c < NT) {
#pragma unroll
                    for (int ks = 0; ks < 8; ++ks)
                        bs[j - NBRES][ks] =
                            *(const s16x8*)&Wf[(size_t)(c * 8 + ks) * 512 + lane * 8];
                }
            }
        }
    };

    int g = blockIdx.x;
    if (g < NSTRIP) { issue(g); issueB(); }
    while (g < NSTRIP) {
        // wait + convert current strip (frees the fp32 prefetch buffer)
        s16x8 a[8];
#pragma unroll
        for (int ks = 0; ks < 8; ++ks) {
            float4 v0 = p0[ks], v1 = p1[ks];
            if constexpr (HasA2) {
                v0.x += q0[ks].x; v0.y += q0[ks].y;
                v0.z += q0[ks].z; v0.w += q0[ks].w;
                v1.x += q1[ks].x; v1.y += q1[ks].y;
                v1.z += q1[ks].z; v1.w += q1[ks].w;
            }
            union { unsigned short u16[8]; s16x8 v; } tmp;
            pk8(v0, v1, tmp.u16);
            a[ks] = tmp.v;
        }
        // grab streamed B for this iteration before re-issuing
        s16x8 bcur[TPW > NBRES ? (TPW - NBRES) : 1][8];
        if constexpr (TPW > NBRES) {
#pragma unroll
            for (int j = 0; j < TPW - NBRES; ++j)
#pragma unroll
                for (int ks = 0; ks < 8; ++ks) bcur[j][ks] = bs[j][ks];
        }
        const int gcur = g;
        g += GEMM_GRID;
        if (g < NSTRIP) { issue(g); issueB(); }  // flies during MFMA phase

#pragma unroll
        for (int j = 0; j < TPW; ++j) {
            int c = wave * TPW + j;
            if (c < NT) {
                f32x4 acc = (f32x4){0.f, 0.f, 0.f, 0.f};
#pragma unroll
                for (int ks = 0; ks < 8; ++ks) {
                    s16x8 b = (j < NBRES) ? bf[j < NBRES ? j : 0][ks]
                                          : bcur[j >= NBRES ? (j - NBRES) : 0][ks];
                    acc = __builtin_amdgcn_mfma_f32_16x16x32_bf16(a[ks], b,
                                                                  acc, 0, 0, 0);
                }
#pragma unroll
                for (int r2 = 0; r2 < 4; ++r2) {
                    size_t row = (size_t)gcur * 16 + quad * 4 + r2;
                    float v = acc[r2] + bias[j];
                    if constexpr (CMODE == 1) {
                        ((unsigned short*)Cv)[(((size_t)(c >> 1) * LQ + row) << 5)
                                              + ((c & 1) << 4) + l15] = f2b(v);
                    } else if constexpr (CMODE == 2) {
                        int col = c * 16 + l15;
                        int hh, jj;
                        if (col < 64) { hh = col >> 3; jj = col & 7; }
                        else          { hh = (col - 64) >> 2; jj = 8 + (col & 3); }
                        ((float*)Cv)[((size_t)hh * LQ + row) * 12 + jj] = v;
                    } else {
                        ((float*)Cv)[row * (NT * 16) + c * 16 + l15] = v;
                    }
                }
            }
        }
    }
}

// Frag-A variant for GEMM4 (A already in fragment layout from sample_kernel),
// same persistent prefetch pipeline (copy-to-compute then issue-next).
template <int NT, int TPW>
__global__ __launch_bounds__(256, 2) void gemm_rs(
    const unsigned short* __restrict__ Af, const unsigned short* __restrict__ Wf,
    const float* __restrict__ b1, float* __restrict__ C)
{
    const int t = threadIdx.x;
    const int wave = t >> 6, lane = t & 63;
    const int l15 = lane & 15, quad = lane >> 4;

    s16x8 bf[TPW][8];
    float bias[TPW];
#pragma unroll
    for (int j = 0; j < TPW; ++j) {
        int c = wave * TPW + j;
#pragma unroll
        for (int ks = 0; ks < 8; ++ks)
            bf[j][ks] = *(const s16x8*)&Wf[(size_t)(c * 8 + ks) * 512 + lane * 8];
        bias[j] = b1[c * 16 + l15];
    }

    s16x8 p[8];
    auto issue = [&](int gs) {
#pragma unroll
        for (int ks = 0; ks < 8; ++ks)
            p[ks] = *(const s16x8*)&Af[(size_t)gs * 4096 + ks * 512 + lane * 8];
    };

    int g = blockIdx.x;
    if (g < NSTRIP) issue(g);
    while (g < NSTRIP) {
        s16x8 a[8];
#pragma unroll
        for (int ks = 0; ks < 8; ++ks) a[ks] = p[ks];   // wait + free buffer
        const int gcur = g;
        g += GEMM_GRID;
        if (g < NSTRIP) issue(g);

#pragma unroll
        for (int j = 0; j < TPW; ++j) {
            int c = wave * TPW + j;
            f32x4 acc = (f32x4){0.f, 0.f, 0.f, 0.f};
#pragma unroll
            for (int ks = 0; ks < 8; ++ks)
                acc = __builtin_amdgcn_mfma_f32_16x16x32_bf16(a[ks], bf[j][ks],
                                                              acc, 0, 0, 0);
#pragma unroll
            for (int r2 = 0; r2 < 4; ++r2) {
                size_t row = (size_t)gcur * 16 + quad * 4 + r2;
                C[row * (NT * 16) + c * 16 + l15] = acc[r2] + bias[j];
            }
        }
    }
}

// ---------------------------------------------------------------------------
// Deformable sampling, head-per-XCD partitioned.
// Block = 256 thr, 64 queries x ONE head; head = blockIdx & 7 so that under
// round-robin block->XCD dispatch each XCD's gather working set is a single
// 2.56 MB head plane (fits the private 4 MB L2).
// raw2 layout: [8][LQ][12] fp32  (8 offsets then 4 attn logits per (h,q)).
// ---------------------------------------------------------------------------
__global__ __launch_bounds__(256) void sample_kernel(
    const float* __restrict__ raw2, const float* __restrict__ rp,
    const unsigned short* __restrict__ value, unsigned short* __restrict__ outa)
{
    __shared__ int4   sIdx[64][4];
    __shared__ float4 sW[64][4];

    const int h = blockIdx.x & 7;
    const int q0 = (blockIdx.x >> 3) * 64;
    const int t = threadIdx.x;
    {   // phase 1: 256 threads = 64 queries x 4 points
        const int qi = t >> 2, p = t & 3;
        const int q = q0 + qi;
        const float* r = raw2 + ((size_t)h * LQ + q) * 12;
        float l0 = r[8], l1 = r[9], l2 = r[10], l3 = r[11];
        float mx = fmaxf(fmaxf(l0, l1), fmaxf(l2, l3));
        float e0 = __expf(l0 - mx), e1 = __expf(l1 - mx);
        float e2 = __expf(l2 - mx), e3 = __expf(l3 - mx);
        float inv = 1.f / (e0 + e1 + e2 + e3);
        float ep = (p == 0) ? e0 : (p == 1) ? e1 : (p == 2) ? e2 : e3;
        float wp = ep * inv;

        float x = rp[(size_t)q * 2 + 0] * (float)WSP - 0.5f + r[p * 2 + 0];
        float y = rp[(size_t)q * 2 + 1] * (float)HSP - 0.5f + r[p * 2 + 1];
        float x0f = floorf(x), y0f = floorf(y);
        int x0 = (int)x0f, y0 = (int)y0f;
        float lw = x - x0f, lh = y - y0f;
        float cw[4] = {(1.f - lh) * (1.f - lw), (1.f - lh) * lw,
                       lh * (1.f - lw), lh * lw};
        int4 I; float4 W;
        int* Ip = &I.x; float* Wp = &W.x;
#pragma unroll
        for (int c = 0; c < 4; ++c) {
            int cx = x0 + (c & 1), cy = y0 + (c >> 1);
            bool valid = (cx >= 0) & (cx < WSP) & (cy >= 0) & (cy < HSP);
            int ccx = cx < 0 ? 0 : (cx > WSP - 1 ? WSP - 1 : cx);
            int ccy = cy < 0 ? 0 : (cy > HSP - 1 ? HSP - 1 : cy);
            Ip[c] = (ccy * WSP + ccx) * DHD;   // element offset within head plane
            Wp[c] = valid ? cw[c] * wp : 0.f;
        }
        sIdx[qi][p] = I;
        sW[qi][p] = W;
    }
    __syncthreads();

    // phase 2: 256 threads = 32 query-pairs x 8 channel-groups
    const int d8 = t & 7, qp = t >> 3;
    const unsigned short* vp = value + (size_t)h * LQ * DHD + d8 * 4;
#pragma unroll
    for (int e = 0; e < 2; ++e) {
        int qi = qp * 2 + e;
        float a0 = 0.f, a1 = 0.f, a2 = 0.f, a3 = 0.f;
#pragma unroll
        for (int p = 0; p < 4; ++p) {
            int4 I = sIdx[qi][p];
            float4 W = sW[qi][p];
            uint2 g0 = *(const uint2*)(vp + I.x);
            uint2 g1 = *(const uint2*)(vp + I.y);
            uint2 g2 = *(const uint2*)(vp + I.z);
            uint2 g3 = *(const uint2*)(vp + I.w);
            a0 += W.x * b2f((unsigned short)g0.x);
            a1 += W.x * b2f((unsigned short)(g0.x >> 16));
            a2 += W.x * b2f((unsigned short)g0.y);
            a3 += W.x * b2f((unsigned short)(g0.y >> 16));
            a0 += W.y * b2f((unsigned short)g1.x);
            a1 += W.y * b2f((unsigned short)(g1.x >> 16));
            a2 += W.y * b2f((unsigned short)g1.y);
            a3 += W.y * b2f((unsigned short)(g1.y >> 16));
            a0 += W.z * b2f((unsigned short)g2.x);
            a1 += W.z * b2f((unsigned short)(g2.x >> 16));
            a2 += W.z * b2f((unsigned short)g2.y);
            a3 += W.z * b2f((unsigned short)(g2.y >> 16));
            a0 += W.w * b2f((unsigned short)g3.x);
            a1 += W.w * b2f((unsigned short)(g3.x >> 16));
            a2 += W.w * b2f((unsigned short)g3.y);
            a3 += W.w * b2f((unsigned short)(g3.y >> 16));
        }
        int q = q0 + qi;
        // A-fragment layout write: c = h*32 + d8*4 + {0..3}
        size_t off = (size_t)(q >> 4) * 4096 + h * 512 + (d8 >> 1) * 128
                   + (q & 15) * 8 + (d8 & 1) * 4;
        union { unsigned short u16[4]; uint2 v; } o;
        o.u16[0] = f2b(a0); o.u16[1] = f2b(a1);
        o.u16[2] = f2b(a2); o.u16[3] = f2b(a3);
        *(uint2*)&outa[off] = o.v;
    }
}

extern "C" void kernel_launch(void* const* d_in, const int* in_sizes, int n_in,
                              void* d_out, int out_size, void* d_ws, size_t ws_size,
                              hipStream_t stream)
{
    const float* query         = (const float*)d_in[0];
    const float* query_pos     = (const float*)d_in[1];
    const float* ref_points    = (const float*)d_in[2];
    const float* input_flatten = (const float*)d_in[3];
    const float* W_value       = (const float*)d_in[4];
    const float* b_value       = (const float*)d_in[5];
    const float* W_off         = (const float*)d_in[6];
    const float* b_off         = (const float*)d_in[7];
    const float* W_attn        = (const float*)d_in[8];
    const float* b_attn        = (const float*)d_in[9];
    const float* W_out         = (const float*)d_in[10];
    const float* b_out         = (const float*)d_in[11];
    float* out = (float*)d_out;

    // workspace: val 20.48MB | raw2 15.36MB | outa 20.48MB | wf 0.31MB
    unsigned short* val  = (unsigned short*)d_ws;                     // [8][LQ][32]
    float*          raw2 = (float*)(val + (size_t)LQ * DMODEL);       // [8][LQ][12]
    unsigned short* outa = (unsigned short*)(raw2 + (size_t)LQ * 96); // A-frag layout
    unsigned short* wf   = outa + (size_t)LQ * DMODEL;                // W-frag bf16
    unsigned short* wfv  = wf;              // slots 0-15
    unsigned short* wfoa = wf + 65536;      // slots 16-21
    unsigned short* wfo  = wf + 90112;      // slots 22-37

    dim3 blk(256);

    // 0) weights -> bf16 fragment order
    convert_weights<<<dim3(76), blk, 0, stream>>>(W_value, W_off, W_attn, W_out, wf);

    // 1) val = bf16(input_flatten) @ Wv^T + b   (value layout, fused transpose)
    gemm_fused<16, 4, 2, 1, false><<<dim3(GEMM_GRID), blk, 0, stream>>>(
        input_flatten, nullptr, wfv, b_value, b_value, 256, val);

    // 2) raw2 = bf16(query + query_pos) @ [Woff;Wattn]^T + [boff;battn]
    gemm_fused<6, 2, 2, 2, true><<<dim3(GEMM_GRID), blk, 0, stream>>>(
        query, query_pos, wfoa, b_off, b_attn, 64, raw2);

    // 3) sampling -> outa (A-fragment layout), head-per-XCD
    sample_kernel<<<dim3(8 * (LQ / 64)), blk, 0, stream>>>(raw2, ref_points, val, outa);

    // 4) out = outa @ W_out^T + b_out
    gemm_rs<16, 4><<<dim3(GEMM_GRID), blk, 0, stream>>>(outa, wfo, b_out, out);
}

// Round 6
// 256.436 us; speedup vs baseline: 1.4657x; 1.4657x over previous
//
#include <hip/hip_runtime.h>
#include <math.h>

#define LQ 40000
#define DMODEL 256
#define NHD 8
#define NPT 4
#define DHD 32
#define HSP 200
#define WSP 200
#define NSTRIP (LQ / 16)   // 2500
#define GEMM_GRID 512      // 2 blocks/CU, all resident
#define RPAD 260           // LDS row stride in floats (16B pad -> 4-bank rotate)

typedef short s16x8 __attribute__((ext_vector_type(8)));
typedef float f32x4 __attribute__((ext_vector_type(4)));

__device__ __forceinline__ unsigned short f2b(float f) {
    unsigned u = __builtin_bit_cast(unsigned, f);
    u += 0x7FFFu + ((u >> 16) & 1u);   // round-to-nearest-even
    return (unsigned short)(u >> 16);
}
__device__ __forceinline__ float b2f(unsigned short u) {
    return __builtin_bit_cast(float, ((unsigned)u) << 16);
}
__device__ __forceinline__ void pk8(const float4& v0, const float4& v1,
                                    unsigned short* o) {
    o[0] = f2b(v0.x); o[1] = f2b(v0.y); o[2] = f2b(v0.z); o[3] = f2b(v0.w);
    o[4] = f2b(v1.x); o[5] = f2b(v1.y); o[6] = f2b(v1.z); o[7] = f2b(v1.w);
}

// ---------------------------------------------------------------------------
// Fragment layouts (16x16x32 bf16 MFMA):
//   A-frag buffer: elem(row, k) at  (row/16)*4096 + ks*512 + lane*8 + j
//       where ks=k/32, quad=(k/8)&3, j=k&7, lane=quad*16+(row&15).
//   W-frag buffer: elem(col, k) at  slot*4096 + ks*512 + lane*8 + j
//       where slot=coltile, lane=quad*16+(col&15). Coalesced b128 per (c,ks).
// ---------------------------------------------------------------------------

// Pre-convert all weights to bf16 fragment order.
// slots: 0-15 W_value, 16-21 [W_off;W_attn] (split 64), 22-37 W_out.
__global__ __launch_bounds__(256) void convert_weights(
    const float* __restrict__ Wv, const float* __restrict__ Woff,
    const float* __restrict__ Wattn, const float* __restrict__ Wout,
    unsigned short* __restrict__ dst)
{
    int u = blockIdx.x * 256 + threadIdx.x;      // 38*8*64 = 19456 exactly
    int lane = u & 63, ks = (u >> 6) & 7, slot = u >> 9;
    int l15 = lane & 15, quad = lane >> 4;
    const float* src;
    if (slot < 16) {
        src = Wv + (size_t)(slot * 16 + l15) * 256;
    } else if (slot < 22) {
        int col = (slot - 16) * 16 + l15;
        src = (col < 64) ? Woff + (size_t)col * 256
                         : Wattn + (size_t)(col - 64) * 256;
    } else {
        src = Wout + (size_t)((slot - 22) * 16 + l15) * 256;
    }
    int k0 = ks * 32 + quad * 8;
    float4 v0 = *(const float4*)(src + k0);
    float4 v1 = *(const float4*)(src + k0 + 4);
    union { unsigned short u16[8]; uint4 v; } tmp;
    pk8(v0, v1, tmp.u16);
    *(uint4*)(dst + (size_t)u * 8) = tmp.v;
}

// ---------------------------------------------------------------------------
// Persistent row-strip GEMM, T14 reg-staged LDS pipeline (standard ds_write —
// no global_load_lds, no cross-barrier DMA).  Per iteration:
//   1. ds_write the register-staged strip (compiler vmcnt waits the loads,
//      which have been in flight since the previous iteration's compute)
//   2. __syncthreads()  -> buffer published
//   3. issue next strip's global loads into registers (fly under MFMA phase)
//   4. ds_read fragments (RPAD rows: consecutive lanes tile the 32 banks),
//      convert fp32->bf16, MFMA, store C
//   5. __syncthreads()  -> all reads done, buffer free
// Staging map: thread t covers row=t>>4, cols (t&15)*4 + j*64 (4 float4s);
// loads are 256B-contiguous per 16-lane run; ds_writes conflict-free.
// CMODE 0: C fp32 row-major [M x NT*16].
// CMODE 1: C bf16 value layout [head][pixel][32ch].
// CMODE 2: C fp32 head-major raw layout [8][LQ][12]  (8 offs + 4 logits).
// ---------------------------------------------------------------------------
template <int NT, int TPW, int CMODE, bool HasA2>
__global__ __launch_bounds__(256, 2) void gemm_fused(
    const float* __restrict__ A, const float* __restrict__ A2,
    const unsigned short* __restrict__ Wf,
    const float* __restrict__ b1, const float* __restrict__ b2, int split,
    void* __restrict__ Cv)
{
    __shared__ float sbuf[HasA2 ? 2 : 1][16][RPAD];   // 16.6 / 33.3 KB

    const int t = threadIdx.x;
    const int wave = t >> 6, lane = t & 63;
    const int l15 = lane & 15, quad = lane >> 4;
    const int srow = t >> 4;            // staging row 0..15
    const int scol = (t & 15) * 4;      // staging col base (floats)

    // Resident B fragments + bias (loaded once per persistent block)
    s16x8 bf[TPW][8];
    float bias[TPW];
#pragma unroll
    for (int j = 0; j < TPW; ++j) {
        bias[j] = 0.f;
        int c = wave * TPW + j;
        if (c < NT) {
#pragma unroll
            for (int ks = 0; ks < 8; ++ks)
                bf[j][ks] = *(const s16x8*)&Wf[(size_t)(c * 8 + ks) * 512 + lane * 8];
            int col = c * 16 + l15;
            bias[j] = (col < split) ? b1[col] : b2[col - split];
        }
    }

    float4 r[HasA2 ? 8 : 4];
    auto issue = [&](int gs) {
        const float* base = A + ((size_t)gs * 16 + srow) * 256 + scol;
#pragma unroll
        for (int j = 0; j < 4; ++j) r[j] = *(const float4*)(base + j * 64);
        if constexpr (HasA2) {
            const float* base2 = A2 + ((size_t)gs * 16 + srow) * 256 + scol;
#pragma unroll
            for (int j = 0; j < 4; ++j) r[4 + j] = *(const float4*)(base2 + j * 64);
        }
    };

    int g = blockIdx.x;                 // always < NSTRIP (512 <= 2500)
    issue(g);
    for (; g < NSTRIP; g += GEMM_GRID) {
        // 1. publish staged strip
#pragma unroll
        for (int j = 0; j < 4; ++j)
            *(float4*)&sbuf[0][srow][scol + j * 64] = r[j];
        if constexpr (HasA2) {
#pragma unroll
            for (int j = 0; j < 4; ++j)
                *(float4*)&sbuf[1][srow][scol + j * 64] = r[4 + j];
        }
        __syncthreads();
        // 3. next strip's loads fly under the compute phase
        if (g + GEMM_GRID < NSTRIP) issue(g + GEMM_GRID);

        // 4. fragments from LDS
        s16x8 a[8];
#pragma unroll
        for (int ks = 0; ks < 8; ++ks) {
            const int k0 = ks * 32 + quad * 8;
            float4 v0 = *(const float4*)&sbuf[0][l15][k0];
            float4 v1 = *(const float4*)&sbuf[0][l15][k0 + 4];
            if constexpr (HasA2) {
                float4 w0 = *(const float4*)&sbuf[1][l15][k0];
                float4 w1 = *(const float4*)&sbuf[1][l15][k0 + 4];
                v0.x += w0.x; v0.y += w0.y; v0.z += w0.z; v0.w += w0.w;
                v1.x += w1.x; v1.y += w1.y; v1.z += w1.z; v1.w += w1.w;
            }
            union { unsigned short u16[8]; s16x8 v; } tmp;
            pk8(v0, v1, tmp.u16);
            a[ks] = tmp.v;
        }

#pragma unroll
        for (int j = 0; j < TPW; ++j) {
            int c = wave * TPW + j;
            if (c < NT) {
                f32x4 acc = (f32x4){0.f, 0.f, 0.f, 0.f};
#pragma unroll
                for (int ks = 0; ks < 8; ++ks)
                    acc = __builtin_amdgcn_mfma_f32_16x16x32_bf16(a[ks], bf[j][ks],
                                                                  acc, 0, 0, 0);
#pragma unroll
                for (int r2 = 0; r2 < 4; ++r2) {
                    size_t row = (size_t)g * 16 + quad * 4 + r2;
                    float v = acc[r2] + bias[j];
                    if constexpr (CMODE == 1) {
                        ((unsigned short*)Cv)[(((size_t)(c >> 1) * LQ + row) << 5)
                                              + ((c & 1) << 4) + l15] = f2b(v);
                    } else if constexpr (CMODE == 2) {
                        int col = c * 16 + l15;
                        int hh, jj;
                        if (col < 64) { hh = col >> 3; jj = col & 7; }
                        else          { hh = (col - 64) >> 2; jj = 8 + (col & 3); }
                        ((float*)Cv)[((size_t)hh * LQ + row) * 12 + jj] = v;
                    } else {
                        ((float*)Cv)[row * (NT * 16) + c * 16 + l15] = v;
                    }
                }
            }
        }
        __syncthreads();               // 5. reads done; buffer reusable
    }
}

// Frag-A variant for GEMM4 (A already in fragment layout from sample_kernel),
// same T14 reg-staged single-buffer pipeline. Strip = 8KB contiguous;
// thread t stages 16B at t*16 and t*16+4096 (coalesced, conflict-free).
template <int NT, int TPW>
__global__ __launch_bounds__(256, 2) void gemm_rs(
    const unsigned short* __restrict__ Af, const unsigned short* __restrict__ Wf,
    const float* __restrict__ b1, float* __restrict__ C)
{
    __shared__ unsigned short sbuf[4096];   // 8 KB

    const int t = threadIdx.x;
    const int wave = t >> 6, lane = t & 63;
    const int l15 = lane & 15, quad = lane >> 4;

    s16x8 bf[TPW][8];
    float bias[TPW];
#pragma unroll
    for (int j = 0; j < TPW; ++j) {
        int c = wave * TPW + j;
#pragma unroll
        for (int ks = 0; ks < 8; ++ks)
            bf[j][ks] = *(const s16x8*)&Wf[(size_t)(c * 8 + ks) * 512 + lane * 8];
        bias[j] = b1[c * 16 + l15];
    }

    uint4 r[2];
    auto issue = [&](int gs) {
        const char* base = (const char*)(Af + (size_t)gs * 4096) + t * 16;
        r[0] = *(const uint4*)base;
        r[1] = *(const uint4*)(base + 4096);
    };

    int g = blockIdx.x;
    issue(g);
    for (; g < NSTRIP; g += GEMM_GRID) {
        *(uint4*)((char*)sbuf + t * 16) = r[0];
        *(uint4*)((char*)sbuf + 4096 + t * 16) = r[1];
        __syncthreads();
        if (g + GEMM_GRID < NSTRIP) issue(g + GEMM_GRID);

        s16x8 a[8];
#pragma unroll
        for (int ks = 0; ks < 8; ++ks)
            a[ks] = *(const s16x8*)((const char*)sbuf + ks * 1024 + lane * 16);

#pragma unroll
        for (int j = 0; j < TPW; ++j) {
            int c = wave * TPW + j;
            f32x4 acc = (f32x4){0.f, 0.f, 0.f, 0.f};
#pragma unroll
            for (int ks = 0; ks < 8; ++ks)
                acc = __builtin_amdgcn_mfma_f32_16x16x32_bf16(a[ks], bf[j][ks],
                                                              acc, 0, 0, 0);
#pragma unroll
            for (int r2 = 0; r2 < 4; ++r2) {
                size_t row = (size_t)g * 16 + quad * 4 + r2;
                C[row * (NT * 16) + c * 16 + l15] = acc[r2] + bias[j];
            }
        }
        __syncthreads();
    }
}

// ---------------------------------------------------------------------------
// Deformable sampling, head-per-XCD partitioned.
// Block = 256 thr, 64 queries x ONE head; head = blockIdx & 7 so that under
// round-robin block->XCD dispatch each XCD's gather working set is a single
// 2.56 MB head plane (fits the private 4 MB L2).
// raw2 layout: [8][LQ][12] fp32  (8 offsets then 4 attn logits per (h,q)).
// ---------------------------------------------------------------------------
__global__ __launch_bounds__(256) void sample_kernel(
    const float* __restrict__ raw2, const float* __restrict__ rp,
    const unsigned short* __restrict__ value, unsigned short* __restrict__ outa)
{
    __shared__ int4   sIdx[64][4];
    __shared__ float4 sW[64][4];

    const int h = blockIdx.x & 7;
    const int q0 = (blockIdx.x >> 3) * 64;
    const int t = threadIdx.x;
    {   // phase 1: 256 threads = 64 queries x 4 points
        const int qi = t >> 2, p = t & 3;
        const int q = q0 + qi;
        const float* r = raw2 + ((size_t)h * LQ + q) * 12;
        float l0 = r[8], l1 = r[9], l2 = r[10], l3 = r[11];
        float mx = fmaxf(fmaxf(l0, l1), fmaxf(l2, l3));
        float e0 = __expf(l0 - mx), e1 = __expf(l1 - mx);
        float e2 = __expf(l2 - mx), e3 = __expf(l3 - mx);
        float inv = 1.f / (e0 + e1 + e2 + e3);
        float ep = (p == 0) ? e0 : (p == 1) ? e1 : (p == 2) ? e2 : e3;
        float wp = ep * inv;

        float x = rp[(size_t)q * 2 + 0] * (float)WSP - 0.5f + r[p * 2 + 0];
        float y = rp[(size_t)q * 2 + 1] * (float)HSP - 0.5f + r[p * 2 + 1];
        float x0f = floorf(x), y0f = floorf(y);
        int x0 = (int)x0f, y0 = (int)y0f;
        float lw = x - x0f, lh = y - y0f;
        float cw[4] = {(1.f - lh) * (1.f - lw), (1.f - lh) * lw,
                       lh * (1.f - lw), lh * lw};
        int4 I; float4 W;
        int* Ip = &I.x; float* Wp = &W.x;
#pragma unroll
        for (int c = 0; c < 4; ++c) {
            int cx = x0 + (c & 1), cy = y0 + (c >> 1);
            bool valid = (cx >= 0) & (cx < WSP) & (cy >= 0) & (cy < HSP);
            int ccx = cx < 0 ? 0 : (cx > WSP - 1 ? WSP - 1 : cx);
            int ccy = cy < 0 ? 0 : (cy > HSP - 1 ? HSP - 1 : cy);
            Ip[c] = (ccy * WSP + ccx) * DHD;   // element offset within head plane
            Wp[c] = valid ? cw[c] * wp : 0.f;
        }
        sIdx[qi][p] = I;
        sW[qi][p] = W;
    }
    __syncthreads();

    // phase 2: 256 threads = 32 query-pairs x 8 channel-groups
    const int d8 = t & 7, qp = t >> 3;
    const unsigned short* vp = value + (size_t)h * LQ * DHD + d8 * 4;
#pragma unroll
    for (int e = 0; e < 2; ++e) {
        int qi = qp * 2 + e;
        float a0 = 0.f, a1 = 0.f, a2 = 0.f, a3 = 0.f;
#pragma unroll
        for (int p = 0; p < 4; ++p) {
            int4 I = sIdx[qi][p];
            float4 W = sW[qi][p];
            uint2 g0 = *(const uint2*)(vp + I.x);
            uint2 g1 = *(const uint2*)(vp + I.y);
            uint2 g2 = *(const uint2*)(vp + I.z);
            uint2 g3 = *(const uint2*)(vp + I.w);
            a0 += W.x * b2f((unsigned short)g0.x);
            a1 += W.x * b2f((unsigned short)(g0.x >> 16));
            a2 += W.x * b2f((unsigned short)g0.y);
            a3 += W.x * b2f((unsigned short)(g0.y >> 16));
            a0 += W.y * b2f((unsigned short)g1.x);
            a1 += W.y * b2f((unsigned short)(g1.x >> 16));
            a2 += W.y * b2f((unsigned short)g1.y);
            a3 += W.y * b2f((unsigned short)(g1.y >> 16));
            a0 += W.z * b2f((unsigned short)g2.x);
            a1 += W.z * b2f((unsigned short)(g2.x >> 16));
            a2 += W.z * b2f((unsigned short)g2.y);
            a3 += W.z * b2f((unsigned short)(g2.y >> 16));
            a0 += W.w * b2f((unsigned short)g3.x);
            a1 += W.w * b2f((unsigned short)(g3.x >> 16));
            a2 += W.w * b2f((unsigned short)g3.y);
            a3 += W.w * b2f((unsigned short)(g3.y >> 16));
        }
        int q = q0 + qi;
        // A-fragment layout write: c = h*32 + d8*4 + {0..3}
        size_t off = (size_t)(q >> 4) * 4096 + h * 512 + (d8 >> 1) * 128
                   + (q & 15) * 8 + (d8 & 1) * 4;
        union { unsigned short u16[4]; uint2 v; } o;
        o.u16[0] = f2b(a0); o.u16[1] = f2b(a1);
        o.u16[2] = f2b(a2); o.u16[3] = f2b(a3);
        *(uint2*)&outa[off] = o.v;
    }
}

extern "C" void kernel_launch(void* const* d_in, const int* in_sizes, int n_in,
                              void* d_out, int out_size, void* d_ws, size_t ws_size,
                              hipStream_t stream)
{
    const float* query         = (const float*)d_in[0];
    const float* query_pos     = (const float*)d_in[1];
    const float* ref_points    = (const float*)d_in[2];
    const float* input_flatten = (const float*)d_in[3];
    const float* W_value       = (const float*)d_in[4];
    const float* b_value       = (const float*)d_in[5];
    const float* W_off         = (const float*)d_in[6];
    const float* b_off         = (const float*)d_in[7];
    const float* W_attn        = (const float*)d_in[8];
    const float* b_attn        = (const float*)d_in[9];
    const float* W_out         = (const float*)d_in[10];
    const float* b_out         = (const float*)d_in[11];
    float* out = (float*)d_out;

    // workspace: val 20.48MB | raw2 15.36MB | outa 20.48MB | wf 0.31MB
    unsigned short* val  = (unsigned short*)d_ws;                     // [8][LQ][32]
    float*          raw2 = (float*)(val + (size_t)LQ * DMODEL);       // [8][LQ][12]
    unsigned short* outa = (unsigned short*)(raw2 + (size_t)LQ * 96); // A-frag layout
    unsigned short* wf   = outa + (size_t)LQ * DMODEL;                // W-frag bf16
    unsigned short* wfv  = wf;              // slots 0-15
    unsigned short* wfoa = wf + 65536;      // slots 16-21
    unsigned short* wfo  = wf + 90112;      // slots 22-37

    dim3 blk(256);

    // 0) weights -> bf16 fragment order
    convert_weights<<<dim3(76), blk, 0, stream>>>(W_value, W_off, W_attn, W_out, wf);

    // 1) val = bf16(input_flatten) @ Wv^T + b   (value layout, fused transpose)
    gemm_fused<16, 4, 1, false><<<dim3(GEMM_GRID), blk, 0, stream>>>(
        input_flatten, nullptr, wfv, b_value, b_value, 256, val);

    // 2) raw2 = bf16(query + query_pos) @ [Woff;Wattn]^T + [boff;battn]
    gemm_fused<6, 2, 2, true><<<dim3(GEMM_GRID), blk, 0, stream>>>(
        query, query_pos, wfoa, b_off, b_attn, 64, raw2);

    // 3) sampling -> outa (A-fragment layout), head-per-XCD
    sample_kernel<<<dim3(8 * (LQ / 64)), blk, 0, stream>>>(raw2, ref_points, val, outa);

    // 4) out = outa @ W_out^T + b_out
    gemm_rs<16, 4><<<dim3(GEMM_GRID), blk, 0, stream>>>(outa, wfo, b_out, out);
}